// Round 10
// baseline (348.308 us; speedup 1.0000x reference)
//
#include <hip/hip_runtime.h>

typedef __bf16 bf16;
typedef __attribute__((ext_vector_type(4))) __bf16 bf16x4;
typedef __attribute__((ext_vector_type(8))) __bf16 bf16x8;
typedef __attribute__((ext_vector_type(4))) float f32x4;

#define MFMA_BF16(A_, B_, C_) __builtin_amdgcn_mfma_f32_16x16x32_bf16(A_, B_, C_, 0, 0, 0)

// Problem dims
#define BB    32
#define SEQ   577
#define CH    768
#define NH    12
#define DHD   64
#define MROWS (BB * SEQ)   // 18464
#define NQKV  2304
#define SEQP  584          // V^T row stride (73*8)
// q scale folded with log2(e): softmax computed in base-2 domain
#define QSCALE 0.1803368801111204f

#define NSTEP 24           // K-steps of 32 (768 = 24*32), both GEMMs

// ---- bijective XCD-chunked remap (m204): hw linear id -> work id such that
// each XCD's round-robin share (ids with equal id&7) is a CONTIGUOUS work range.
__device__ __forceinline__ int xcd_chunk(int bid, int nwg) {
  int q8 = nwg >> 3, r8 = nwg & 7;
  int xcd = bid & 7, sub = bid >> 3;
  return (xcd < r8 ? xcd * (q8 + 1) : r8 * (q8 + 1) + (xcd - r8) * q8) + sub;
}

// ---- async global->LDS 16B (wave-uniform LDS base + lane*16, per guide §5) ----
__device__ __forceinline__ void async_ld16(const bf16* g, bf16* l) {
  __builtin_amdgcn_global_load_lds(
      (const __attribute__((address_space(1))) void*)g,
      (__attribute__((address_space(3))) void*)l, 16, 0, 0);
}

// ---- fp32 -> bf16 convert ----
__global__ __launch_bounds__(256) void cvt_bf16(const float* __restrict__ src,
                                                bf16* __restrict__ dst, int n) {
  int idx = (blockIdx.x * 256 + threadIdx.x) * 4;
  if (idx >= n) return;
  float4 v = *(const float4*)(src + idx);
  bf16x4 o = {(bf16)v.x, (bf16)v.y, (bf16)v.z, (bf16)v.w};
  *(bf16x4*)(dst + idx) = o;
}

// ---- zero the 7-element pad of each V^T row (j in [577,584)) so attention's
// staged V reads at clamped chunk start 576 see zeros beyond j=576.
__global__ __launch_bounds__(256) void pad_v(bf16* __restrict__ vt) {
  int r = blockIdx.x * 256 + threadIdx.x;
  if (r < BB * NH * DHD) {
    bf16* p = vt + (size_t)r * SEQP + SEQ;
#pragma unroll
    for (int i = 0; i < 7; ++i) p[i] = (bf16)0.f;
  }
}

// ---- 128x128x(K=768) bf16 MFMA GEMM (qkv) ----
// R10: counted-vmcnt pipeline on the 128^2 tile. Diagnosis: the 2-barrier loop
// stalled ~2200cyc/stage (drain issued only ~640cyc earlier; HBM-latency class,
// FETCH=4.2x unique). New loop: THREE 32-K LDS buffers (48KB -> 3 blocks/CU),
// prefetch distance 2, per iter s:
//   vmcnt(4)   -> stage s landed; stage s+1 STAYS IN FLIGHT across the barrier
//   s_barrier  -> all waves' stage-s loads visible; buf[(s+2)%3] free to write
//   ISSUE(s+2) -> drained 2 iterations later (~1600-2000cyc slack >= HBM lat)
//   COMPUTE(s%3)
// Race-free: ISSUE(s+2) overwrites buf[(s-1)%3], last read in COMPUTE(s-1),
// separated by barrier(s) in every wave's program order.
// Plus R8-verified XCD-chunked swizzle (FETCH 133->57.6MB).
// qkv epilogue: q -> qrm [M,768] (scaled), k -> krm [M,768], v -> vt [B,H,64,SEQP]
__global__ __launch_bounds__(256, 3)
void gemm_qkv(const bf16* __restrict__ A, const bf16* __restrict__ W,
              const float* __restrict__ bias,
              bf16* __restrict__ qrm, bf16* __restrict__ krm, bf16* __restrict__ vt) {
  __shared__ bf16 As[3][128 * 32];   // [buf][row*32 + chunk*8], 8KB each
  __shared__ bf16 Bs[3][128 * 32];
  const int tid = threadIdx.x, lane = tid & 63, wid = tid >> 6;
  const int quad = lane >> 4, r15 = lane & 15;
  const int nbx = (int)gridDim.x;
  const int wg = xcd_chunk((int)blockIdx.y * nbx + (int)blockIdx.x,
                           nbx * (int)gridDim.y);
  const int m0 = (wg / nbx) * 128, n0 = (wg % nbx) * 128;
  const int waveM = wid & 1, waveN = wid >> 1;

  // staging: 512 16B chunks per 32-K tile; XOR chunk swizzle -> frag reads 2-way (free)
  const bf16* aSrc[2];
  const bf16* bSrc[2];
  for (int c = 0; c < 2; ++c) {
    int q = wid * 128 + c * 64 + lane;
    int row = q >> 2;
    int sw = (row ^ (row >> 2)) & 3;
    int kc = (q & 3) ^ sw;
    aSrc[c] = A + (size_t)(m0 + row) * CH + kc * 8;
    bSrc[c] = W + (size_t)(n0 + row) * CH + kc * 8;
  }

  f32x4 acc[4][4];
#pragma unroll
  for (int i = 0; i < 4; ++i)
#pragma unroll
    for (int j = 0; j < 4; ++j) acc[i][j] = (f32x4){0.f, 0.f, 0.f, 0.f};

#define QISSUE(S)                                                         \
  {                                                                       \
    const int kb_ = (S) * 32;                                             \
    const int bf_ = (S) % 3;                                              \
    _Pragma("unroll") for (int c = 0; c < 2; ++c) {                       \
      async_ld16(aSrc[c] + kb_, &As[bf_][(wid * 128 + c * 64) * 8]);      \
      async_ld16(bSrc[c] + kb_, &Bs[bf_][(wid * 128 + c * 64) * 8]);      \
    }                                                                     \
  }

#define QCOMPUTE(BF)                                                      \
  {                                                                       \
    bf16x8 af[4], bfr[4];                                                 \
    _Pragma("unroll") for (int s_ = 0; s_ < 4; ++s_) {                    \
      int rowA = waveM * 64 + s_ * 16 + r15;                              \
      int ca = quad ^ ((rowA ^ (rowA >> 2)) & 3);                         \
      af[s_] = *(const bf16x8*)(&As[BF][rowA * 32 + ca * 8]);             \
      int rowB = waveN * 64 + s_ * 16 + r15;                              \
      int cb = quad ^ ((rowB ^ (rowB >> 2)) & 3);                         \
      bfr[s_] = *(const bf16x8*)(&Bs[BF][rowB * 32 + cb * 8]);            \
    }                                                                     \
    _Pragma("unroll") for (int sm = 0; sm < 4; ++sm)                      \
      _Pragma("unroll") for (int sn = 0; sn < 4; ++sn)                    \
        acc[sm][sn] = MFMA_BF16(af[sm], bfr[sn], acc[sm][sn]);            \
  }

  QISSUE(0);
  QISSUE(1);
  for (int s = 0; s < NSTEP; ++s) {
    if (s < NSTEP - 1) {
      asm volatile("s_waitcnt vmcnt(4)" ::: "memory");  // stage s landed; s+1 in flight
    } else {
      asm volatile("s_waitcnt vmcnt(0)" ::: "memory");  // tail drain
    }
    __builtin_amdgcn_s_barrier();
    asm volatile("" ::: "memory");
    if (s < NSTEP - 2) QISSUE(s + 2);
    QCOMPUTE(s % 3);
  }

  // epilogue: C/D layout row=(lane>>4)*4+reg, col=lane&15 (verified m89/m91)
  int t = (n0 >= 1536) ? 2 : (n0 >= 768 ? 1 : 0);  // 128-tiles never straddle 768
#pragma unroll
  for (int sn = 0; sn < 4; ++sn) {
    int gn = n0 + waveN * 64 + sn * 16 + r15;
    float bv = bias[gn];
    int col = gn - t * CH;  // [0,768)
    int h = col >> 6, d = col & 63;
#pragma unroll
    for (int sm = 0; sm < 4; ++sm) {
      int gmBase = m0 + waveM * 64 + sm * 16 + quad * 4;
#pragma unroll
      for (int r = 0; r < 4; ++r) {
        int gm = gmBase + r;
        if (gm < MROWS) {
          float v = acc[sm][sn][r] + bv;
          if (t == 0) {
            qrm[(size_t)gm * CH + col] = (bf16)(v * QSCALE);
          } else if (t == 1) {
            krm[(size_t)gm * CH + col] = (bf16)v;
          } else {
            int b_ = gm / SEQ;
            int n_ = gm - b_ * SEQ;
            vt[((size_t)(b_ * NH + h) * DHD + d) * SEQP + n_] = (bf16)v;
          }
        }
      }
    }
  }
}
#undef QISSUE
#undef QCOMPUTE

// ---- 256x256x(K=768) proj GEMM, R3-proven (single 219-block round). ----
// Counted-vmcnt pipeline, 4 LDS buffers, prefetch distance 2, one raw s_barrier
// per 32-K step.
__global__ __launch_bounds__(512, 2)
void gemm_proj(const bf16* __restrict__ A, const bf16* __restrict__ W,
               const float* __restrict__ bias, float* __restrict__ out) {
  __shared__ bf16 As[4][256 * 32];  // [buf][row*32 + chunk2*8], 16 KiB each
  __shared__ bf16 Bs[4][256 * 32];
  const int tid = threadIdx.x, lane = tid & 63, wid = tid >> 6;
  const int quad = lane >> 4, r15 = lane & 15;

  const int nbx = (int)gridDim.x;
  const int wg = xcd_chunk((int)blockIdx.y * nbx + (int)blockIdx.x,
                           nbx * (int)gridDim.y);
  const int m0 = (wg / nbx) * 256, n0 = (wg % nbx) * 256;

  const int rm = (wid >> 2) * 128;  // wave row base (2 waves in M)
  const int rn = (wid & 3) * 64;    // wave col base (4 waves in N)

  int aOff[2], bOff[2];
#pragma unroll
  for (int i = 0; i < 2; ++i) {
    int slot = i * 512 + tid;
    int row = slot >> 2, pc2 = slot & 3;
    int gc2 = pc2 ^ ((row ^ (row >> 2)) & 3);
    aOff[i] = (m0 + row) * CH + gc2 * 8;
    bOff[i] = (n0 + row) * CH + gc2 * 8;
  }

  f32x4 acc[8][4];
#pragma unroll
  for (int i = 0; i < 8; ++i)
#pragma unroll
    for (int j = 0; j < 4; ++j) acc[i][j] = (f32x4){0.f, 0.f, 0.f, 0.f};

#define ISSUE2(S)                                                              \
  {                                                                            \
    const int kb_ = (S) * 32;                                                  \
    const int bf_ = (S) & 3;                                                   \
    _Pragma("unroll") for (int i = 0; i < 2; ++i) {                            \
      async_ld16(A + aOff[i] + kb_, &As[bf_][(i * 512 + tid) * 8]);            \
      async_ld16(W + bOff[i] + kb_, &Bs[bf_][(i * 512 + tid) * 8]);            \
    }                                                                          \
  }

#define COMPUTE2(BF)                                                           \
  {                                                                            \
    bf16x8 bfr[4], afr[8];                                                     \
    _Pragma("unroll") for (int sn = 0; sn < 4; ++sn) {                         \
      int fr = rn + sn * 16 + r15;                                             \
      int pc2 = quad ^ ((fr ^ (fr >> 2)) & 3);                                 \
      bfr[sn] = *(const bf16x8*)(&Bs[BF][fr * 32 + pc2 * 8]);                  \
    }                                                                          \
    _Pragma("unroll") for (int sm = 0; sm < 8; ++sm) {                         \
      int fr = rm + sm * 16 + r15;                                             \
      int pc2 = quad ^ ((fr ^ (fr >> 2)) & 3);                                 \
      afr[sm] = *(const bf16x8*)(&As[BF][fr * 32 + pc2 * 8]);                  \
    }                                                                          \
    _Pragma("unroll") for (int sm = 0; sm < 8; ++sm)                           \
      _Pragma("unroll") for (int sn = 0; sn < 4; ++sn)                         \
        acc[sm][sn] = MFMA_BF16(afr[sm], bfr[sn], acc[sm][sn]);                \
  }

  ISSUE2(0);
  ISSUE2(1);
  for (int s = 0; s < NSTEP; ++s) {
    if (s < NSTEP - 2) {
      ISSUE2(s + 2);
      asm volatile("s_waitcnt vmcnt(8)" ::: "memory");
    } else if (s == NSTEP - 2) {
      asm volatile("s_waitcnt vmcnt(4)" ::: "memory");
    } else {
      asm volatile("s_waitcnt vmcnt(0)" ::: "memory");
    }
    __builtin_amdgcn_s_barrier();
    asm volatile("" ::: "memory");
    COMPUTE2(s & 3);
  }

  // epilogue: bias + fp32 out
#pragma unroll
  for (int sn = 0; sn < 4; ++sn) {
    int gn = n0 + rn + sn * 16 + r15;
    float bv = bias[gn];
#pragma unroll
    for (int sm = 0; sm < 8; ++sm) {
      int gmBase = m0 + rm + sm * 16 + quad * 4;
#pragma unroll
      for (int r = 0; r < 4; ++r) {
        int gm = gmBase + r;
        if (gm < MROWS) out[(size_t)gm * CH + gn] = acc[sm][sn][r] + bv;
      }
    }
  }
}
#undef ISSUE2
#undef COMPUTE2

// ---- flash attention, NO-MAX softmax, base-2 domain, swapped QK^T (R6),
// GEMM-style async double-buffered staging (R7), XCD-chunked blocks (R8),
// tail peel (R9). Unchanged from R9. ----
__global__ __launch_bounds__(256, 3)
void attn_kernel(const bf16* __restrict__ qrm, const bf16* __restrict__ krm,
                 const bf16* __restrict__ vt, bf16* __restrict__ ob) {
  __shared__ bf16 Ks[2][128 * 32];     // K tile [hr = j_loc*2+half][32], XOR-swizzled
  __shared__ bf16 Vt[2][128 * 32];     // V^T tile [hr = d*2+half][32], XOR-swizzled
  __shared__ bf16 Ps[4][2][16 * 72];   // per-wave, per-group private P [m][j] pad 72
  const int tid = threadIdx.x, lane = tid & 63, wid = tid >> 6;
  const int quad = lane >> 4, r15 = lane & 15;
  const int nbx = (int)gridDim.x;  // 5
  const int wg = xcd_chunk((int)blockIdx.y * nbx + (int)blockIdx.x,
                           nbx * (int)gridDim.y);
  const int qt = wg % nbx, bh = wg / nbx;
  const int b_ = bh / NH, h = bh - b_ * NH;
  const bf16* vtb = vt + (size_t)bh * DHD * SEQP;
  const bf16* krmb = krm + (size_t)b_ * SEQ * CH + h * DHD;

  // Per-thread staging: slot q = wid*128 + c*64 + lane -> hr = q>>2 in [0,128),
  // logical chunk kc = (q&3)^sw(hr); element offset off = (hr&1)*32 + kc*8.
  // Running pointers advance +64*CH (K) / +64 (V) per clean tile.
  int jloc_[2], off_[2];
  const bf16* kp_[2];
  const bf16* vp_[2];
#pragma unroll
  for (int c = 0; c < 2; ++c) {
    int q = wid * 128 + c * 64 + lane;
    int hr = q >> 2;
    int kc = (q & 3) ^ ((hr ^ (hr >> 2)) & 3);
    jloc_[c] = hr >> 1;                    // K: local j row; V: d row
    off_[c] = (hr & 1) * 32 + kc * 8;      // K: d offset;   V: local j offset
    kp_[c] = krmb + (size_t)jloc_[c] * CH + off_[c];
    vp_[c] = vtb + (size_t)jloc_[c] * SEQP + off_[c];
  }

#define ASTAGE_CLEAN(BUF)                                                      \
  {                                                                            \
    _Pragma("unroll") for (int c = 0; c < 2; ++c) {                            \
      async_ld16(kp_[c], &Ks[BUF][(wid * 128 + c * 64) * 8]);                  \
      async_ld16(vp_[c], &Vt[BUF][(wid * 128 + c * 64) * 8]);                  \
      kp_[c] += 64 * CH;                                                       \
      vp_[c] += 64;                                                            \
    }                                                                          \
  }

  // Tile 9 (j0=576): every K row and V chunk start clamps to j=576.
#define ASTAGE_TAIL(BUF)                                                       \
  {                                                                            \
    _Pragma("unroll") for (int c = 0; c < 2; ++c) {                            \
      async_ld16(krmb + (size_t)(SEQ - 1) * CH + off_[c],                      \
                 &Ks[BUF][(wid * 128 + c * 64) * 8]);                          \
      async_ld16(vtb + (size_t)jloc_[c] * SEQP + (SEQ - 1),                    \
                 &Vt[BUF][(wid * 128 + c * 64) * 8]);                          \
    }                                                                          \
  }

  // Q fragments resident for both row groups (MFMA B operand: n=lane&15=q-row,
  // k=quad*8+j). q pre-scaled by 0.125*log2e.
  bf16x8 qf[2][2];
#pragma unroll
  for (int g = 0; g < 2; ++g) {
    int qrow = qt * 128 + wid * 32 + g * 16 + r15;
    if (qrow > SEQ - 1) qrow = SEQ - 1;
    const bf16* qp = qrm + (size_t)(b_ * SEQ + qrow) * CH + h * DHD + quad * 8;
    qf[g][0] = *(const bf16x8*)qp;
    qf[g][1] = *(const bf16x8*)(qp + 32);
  }

  f32x4 oacc[2][4];
#pragma unroll
  for (int g = 0; g < 2; ++g)
#pragma unroll
    for (int i = 0; i < 4; ++i) oacc[g][i] = (f32x4){0.f, 0.f, 0.f, 0.f};
  float lrow0 = 0.f, lrow1 = 0.f;  // per-lane partial row sum (row m = r15)

  bf16* P0 = &Ps[wid][0][0];
  bf16* P1 = &Ps[wid][1][0];

  // Shared compute body. MASKED=1 only for tile 9 (j0=576).
#define QKT_PV(BUF, MASKED)                                                    \
  {                                                                            \
    f32x4 s0[4], s1[4];                                                        \
    _Pragma("unroll") for (int sj = 0; sj < 4; ++sj) {                         \
      int hr0 = (sj * 16 + r15) * 2, hr1 = hr0 + 1;                            \
      int p0c = quad ^ ((hr0 ^ (hr0 >> 2)) & 3);                               \
      int p1c = quad ^ ((hr1 ^ (hr1 >> 2)) & 3);                               \
      bf16x8 kf0 = *(const bf16x8*)(&Ks[BUF][hr0 * 32 + p0c * 8]);             \
      bf16x8 kf1 = *(const bf16x8*)(&Ks[BUF][hr1 * 32 + p1c * 8]);             \
      f32x4 z = (f32x4){0.f, 0.f, 0.f, 0.f};                                   \
      s0[sj] = MFMA_BF16(kf0, qf[0][0], z);                                    \
      s0[sj] = MFMA_BF16(kf1, qf[0][1], s0[sj]);                               \
      s1[sj] = MFMA_BF16(kf0, qf[1][0], z);                                    \
      s1[sj] = MFMA_BF16(kf1, qf[1][1], s1[sj]);                               \
    }                                                                          \
    _Pragma("unroll") for (int sj = 0; sj < 4; ++sj)                           \
      _Pragma("unroll") for (int r = 0; r < 4; ++r) {                          \
        float e0, e1;                                                          \
        if (MASKED) {                                                          \
          bool ok = (sj == 0) && (quad == 0) && (r == 0); /* j==576 only */    \
          e0 = ok ? __builtin_amdgcn_exp2f(s0[sj][r]) : 0.f;                   \
          e1 = ok ? __builtin_amdgcn_exp2f(s1[sj][r]) : 0.f;                   \
        } else {                                                               \
          e0 = __builtin_amdgcn_exp2f(s0[sj][r]);                              \
          e1 = __builtin_amdgcn_exp2f(s1[sj][r]);                              \
        }                                                                      \
        s0[sj][r] = e0; lrow0 += e0;                                           \
        s1[sj][r] = e1; lrow1 += e1;                                           \
      }                                                                        \
    _Pragma("unroll") for (int sj = 0; sj < 4; ++sj) {                         \
      bf16x4 p0 = {(bf16)s0[sj][0], (bf16)s0[sj][1],                           \
                   (bf16)s0[sj][2], (bf16)s0[sj][3]};                          \
      bf16x4 p1 = {(bf16)s1[sj][0], (bf16)s1[sj][1],                           \
                   (bf16)s1[sj][2], (bf16)s1[sj][3]};                          \
      *(bf16x4*)(P0 + r15 * 72 + sj * 16 + quad * 4) = p0;                     \
      *(bf16x4*)(P1 + r15 * 72 + sj * 16 + quad * 4) = p1;                     \
    }                                                                          \
    asm volatile("s_waitcnt lgkmcnt(0)" ::: "memory"); /* wave-private RAW */  \
    _Pragma("unroll") for (int kc = 0; kc < 2; ++kc) {                         \
      bf16x8 pf0 = *(const bf16x8*)(P0 + r15 * 72 + kc * 32 + quad * 8);       \
      bf16x8 pf1 = *(const bf16x8*)(P1 + r15 * 72 + kc * 32 + quad * 8);       \
      _Pragma("unroll") for (int sd = 0; sd < 4; ++sd) {                       \
        int hrv = (sd * 16 + r15) * 2 + kc;                                    \
        int pv = quad ^ ((hrv ^ (hrv >> 2)) & 3);                              \
        bf16x8 vf = *(const bf16x8*)(&Vt[BUF][hrv * 32 + pv * 8]);             \
        oacc[0][sd] = MFMA_BF16(pf0, vf, oacc[0][sd]);                         \
        oacc[1][sd] = MFMA_BF16(pf1, vf, oacc[1][sd]);                         \
      }                                                                        \
    }                                                                          \
  }

  ASTAGE_CLEAN(0);
  int buf = 0;
  for (int t = 0; t < 9; ++t) {
    __syncthreads();  // drains stage(t) (issued one full tile ago) + buf reuse safe
    if (t < 8) { ASTAGE_CLEAN(buf ^ 1); } else { ASTAGE_TAIL(buf ^ 1); }
    QKT_PV(buf, 0);
    buf ^= 1;
  }
  __syncthreads();    // drains tile-9 stage
  QKT_PV(buf, 1);     // tile 9: only j=576 valid
#undef ASTAGE_CLEAN
#undef ASTAGE_TAIL
#undef QKT_PV

  // Row sums: reduce across the 4 lanes sharing r15 (quads) -> full sum at every lane.
  lrow0 += __shfl_xor(lrow0, 16);
  lrow0 += __shfl_xor(lrow0, 32);
  lrow1 += __shfl_xor(lrow1, 16);
  lrow1 += __shfl_xor(lrow1, 32);

  // write O -> attn_out [b*577+n][h*64+d]; O C/D layout: row m=quad*4+r, col d=sd*16+r15.
  // Row sum for m lives at lanes with r15==m -> fetch via one shuffle (src lane = m).
#pragma unroll
  for (int g = 0; g < 2; ++g) {
    float lr = (g == 0) ? lrow0 : lrow1;
#pragma unroll
    for (int r = 0; r < 4; ++r) {
      int m = quad * 4 + r;
      float rs = __shfl(lr, m);
      int orow = qt * 128 + wid * 32 + g * 16 + m;
      if (orow < SEQ) {
        float inv = 1.0f / rs;
        size_t rowoff = ((size_t)(b_ * SEQ + orow)) * CH + h * DHD;
#pragma unroll
        for (int sd = 0; sd < 4; ++sd)
          ob[rowoff + sd * 16 + r15] = (bf16)(oacc[g][sd][r] * inv);
      }
    }
  }
}

extern "C" void kernel_launch(void* const* d_in, const int* in_sizes, int n_in,
                              void* d_out, int out_size, void* d_ws, size_t ws_size,
                              hipStream_t stream) {
  const float* x      = (const float*)d_in[0];
  const float* qkv_w  = (const float*)d_in[1];
  const float* qkv_b  = (const float*)d_in[2];
  const float* proj_w = (const float*)d_in[3];
  const float* proj_b = (const float*)d_in[4];
  float* out = (float*)d_out;

  char* w = (char*)d_ws;
  // workspace layout (bytes), total 117,325,824:
  bf16* xb  = (bf16*)(w);               // [18464,768] x_bf16, reused as attn_out
  bf16* wqp = (bf16*)(w + 28360704);    // qkv_w bf16; later aliased by proj_w bf16
  bf16* qrm = (bf16*)(w + 31899648);    // [18464,768] scaled Q
  bf16* krm = (bf16*)(w + 60260352);    // [18464,768] K
  bf16* vtb = (bf16*)(w + 88621056);    // [32,12,64,584] V^T
  // GEMM m-tail reads spill into the wqp region: finite, discarded.

  cvt_bf16<<<(MROWS * CH / 4 + 255) / 256, 256, 0, stream>>>(x, xb, MROWS * CH);
  cvt_bf16<<<(NQKV * CH / 4 + 255) / 256, 256, 0, stream>>>(qkv_w, wqp, NQKV * CH);
  pad_v<<<(BB * NH * DHD + 255) / 256, 256, 0, stream>>>(vtb);

  gemm_qkv<<<dim3(NQKV / 128, 145), 256, 0, stream>>>(
      xb, wqp, qkv_b, qrm, krm, vtb);

  attn_kernel<<<dim3(5, BB * NH), 256, 0, stream>>>(qrm, krm, vtb, xb);

  // proj weights convert AFTER attention (stream-ordered) so it can alias wqp
  cvt_bf16<<<(CH * CH / 4 + 255) / 256, 256, 0, stream>>>(proj_w, wqp, CH * CH);

  gemm_proj<<<dim3(CH / 256, 73), 512, 0, stream>>>(xb, wqp, proj_b, out);
}

// Round 11
// 339.445 us; speedup vs baseline: 1.0261x; 1.0261x over previous
//
#include <hip/hip_runtime.h>

typedef __bf16 bf16;
typedef __attribute__((ext_vector_type(4))) __bf16 bf16x4;
typedef __attribute__((ext_vector_type(8))) __bf16 bf16x8;
typedef __attribute__((ext_vector_type(4))) float f32x4;

#define MFMA_BF16(A_, B_, C_) __builtin_amdgcn_mfma_f32_16x16x32_bf16(A_, B_, C_, 0, 0, 0)

// Problem dims
#define BB    32
#define SEQ   577
#define CH    768
#define NH    12
#define DHD   64
#define MROWS (BB * SEQ)   // 18464
#define NQKV  2304
#define SEQP  584          // V^T row stride (73*8)
// q scale folded with log2(e): softmax computed in base-2 domain
#define QSCALE 0.1803368801111204f

#define NSTEP 24           // K-steps of 32 for the 256^2 proj GEMM (768 = 24*32)

// ---- bijective XCD-chunked remap (m204): hw linear id -> work id such that
// each XCD's round-robin share (ids with equal id&7) is a CONTIGUOUS work range.
__device__ __forceinline__ int xcd_chunk(int bid, int nwg) {
  int q8 = nwg >> 3, r8 = nwg & 7;
  int xcd = bid & 7, sub = bid >> 3;
  return (xcd < r8 ? xcd * (q8 + 1) : r8 * (q8 + 1) + (xcd - r8) * q8) + sub;
}

// ---- async global->LDS 16B (wave-uniform LDS base + lane*16, per guide §5) ----
__device__ __forceinline__ void async_ld16(const bf16* g, bf16* l) {
  __builtin_amdgcn_global_load_lds(
      (const __attribute__((address_space(1))) void*)g,
      (__attribute__((address_space(3))) void*)l, 16, 0, 0);
}

// ---- fp32 -> bf16 convert ----
__global__ __launch_bounds__(256) void cvt_bf16(const float* __restrict__ src,
                                                bf16* __restrict__ dst, int n) {
  int idx = (blockIdx.x * 256 + threadIdx.x) * 4;
  if (idx >= n) return;
  float4 v = *(const float4*)(src + idx);
  bf16x4 o = {(bf16)v.x, (bf16)v.y, (bf16)v.z, (bf16)v.w};
  *(bf16x4*)(dst + idx) = o;
}

// ---- zero the 7-element pad of each V^T row (j in [577,584)) so attention's
// staged V reads at clamped chunk start 576 see zeros beyond j=576.
__global__ __launch_bounds__(256) void pad_v(bf16* __restrict__ vt) {
  int r = blockIdx.x * 256 + threadIdx.x;
  if (r < BB * NH * DHD) {
    bf16* p = vt + (size_t)r * SEQP + SEQ;
#pragma unroll
    for (int i = 0; i < 7; ++i) p[i] = (bf16)0.f;
  }
}

// ---- 128x128x(K=768) bf16 MFMA GEMM (qkv), R8-best config ----
// R0-proven double-buffered single-barrier K-loop at (256,2) + XCD-chunked
// swizzle (FETCH 133->57.6MB, R8-measured; R9 A/B showed R8's profiled dur
// regression was throttle noise -- wallclock best total was R8's 340.5us).
// R11: qkv frozen at this config. Five structural variants (drain-0 2-buf,
// occupancy-5, 256^2 1-buf, 256^2 counted-vmcnt, 128^2 counted-vmcnt) all
// landed 145-175us -> 145us is this shape's plateau for the 128^2 family.
// qkv epilogue: q -> qrm [M,768] (scaled), k -> krm [M,768], v -> vt [B,H,64,SEQP]
__global__ __launch_bounds__(256, 2)
void gemm_qkv(const bf16* __restrict__ A, const bf16* __restrict__ W,
              const float* __restrict__ bias,
              bf16* __restrict__ qrm, bf16* __restrict__ krm, bf16* __restrict__ vt) {
  __shared__ bf16 As[2][128 * 32];
  __shared__ bf16 Bs[2][128 * 32];
  const int tid = threadIdx.x, lane = tid & 63, wid = tid >> 6;
  const int quad = lane >> 4, r15 = lane & 15;
  const int nbx = (int)gridDim.x;
  const int wg = xcd_chunk((int)blockIdx.y * nbx + (int)blockIdx.x,
                           nbx * (int)gridDim.y);
  const int m0 = (wg / nbx) * 128, n0 = (wg % nbx) * 128;
  const int waveM = wid & 1, waveN = wid >> 1;

  // staging: 512 16B chunks per tile; XOR chunk swizzle -> fragment ds_read_b128 2-way (free)
  const bf16* aSrc[2];
  const bf16* bSrc[2];
  for (int c = 0; c < 2; ++c) {
    int q = wid * 128 + c * 64 + lane;
    int row = q >> 2;
    int sw = (row ^ (row >> 2)) & 3;
    int kc = (q & 3) ^ sw;
    aSrc[c] = A + (size_t)(m0 + row) * CH + kc * 8;
    bSrc[c] = W + (size_t)(n0 + row) * CH + kc * 8;
  }

  f32x4 acc[4][4];
#pragma unroll
  for (int i = 0; i < 4; ++i)
#pragma unroll
    for (int j = 0; j < 4; ++j) acc[i][j] = (f32x4){0.f, 0.f, 0.f, 0.f};

#define GSTAGE(K0, BUF)                                                   \
  {                                                                       \
    _Pragma("unroll") for (int c = 0; c < 2; ++c) {                       \
      async_ld16(aSrc[c] + (K0), &As[BUF][(wid * 128 + c * 64) * 8]);     \
      async_ld16(bSrc[c] + (K0), &Bs[BUF][(wid * 128 + c * 64) * 8]);     \
    }                                                                     \
  }

#define GCOMPUTE(BUF)                                                     \
  {                                                                       \
    bf16x8 af[4], bfr[4];                                                 \
    _Pragma("unroll") for (int s = 0; s < 4; ++s) {                       \
      int rowA = waveM * 64 + s * 16 + r15;                               \
      int ca = quad ^ ((rowA ^ (rowA >> 2)) & 3);                         \
      af[s] = *(const bf16x8*)(&As[BUF][rowA * 32 + ca * 8]);             \
      int rowB = waveN * 64 + s * 16 + r15;                               \
      int cb = quad ^ ((rowB ^ (rowB >> 2)) & 3);                         \
      bfr[s] = *(const bf16x8*)(&Bs[BUF][rowB * 32 + cb * 8]);            \
    }                                                                     \
    _Pragma("unroll") for (int sm = 0; sm < 4; ++sm)                      \
      _Pragma("unroll") for (int sn = 0; sn < 4; ++sn)                    \
        acc[sm][sn] = MFMA_BF16(af[sm], bfr[sn], acc[sm][sn]);            \
  }

  GSTAGE(0, 0);
  for (int k0 = 0; k0 < CH; k0 += 64) {
    __syncthreads();                       // drains buf0 loads (issued prev iter / prologue)
    GSTAGE(k0 + 32, 1);                    // overlaps compute on buf0
    GCOMPUTE(0);
    __syncthreads();                       // drains buf1 loads; all waves done with buf0
    if (k0 + 64 < CH) GSTAGE(k0 + 64, 0);  // overlaps compute on buf1
    GCOMPUTE(1);
  }

  // epilogue: C/D layout row=(lane>>4)*4+reg, col=lane&15 (verified m89/m91)
  int t = (n0 >= 1536) ? 2 : (n0 >= 768 ? 1 : 0);  // 128-tiles never straddle 768
#pragma unroll
  for (int sn = 0; sn < 4; ++sn) {
    int gn = n0 + waveN * 64 + sn * 16 + r15;
    float bv = bias[gn];
    int col = gn - t * CH;  // [0,768)
    int h = col >> 6, d = col & 63;
#pragma unroll
    for (int sm = 0; sm < 4; ++sm) {
      int gmBase = m0 + waveM * 64 + sm * 16 + quad * 4;
#pragma unroll
      for (int r = 0; r < 4; ++r) {
        int gm = gmBase + r;
        if (gm < MROWS) {
          float v = acc[sm][sn][r] + bv;
          if (t == 0) {
            qrm[(size_t)gm * CH + col] = (bf16)(v * QSCALE);
          } else if (t == 1) {
            krm[(size_t)gm * CH + col] = (bf16)v;
          } else {
            int b_ = gm / SEQ;
            int n_ = gm - b_ * SEQ;
            vt[((size_t)(b_ * NH + h) * DHD + d) * SEQP + n_] = (bf16)v;
          }
        }
      }
    }
  }
}
#undef GSTAGE
#undef GCOMPUTE

// ---- 256x256x(K=768) proj GEMM, R3-proven (single 219-block round). ----
// Counted-vmcnt pipeline, 4 LDS buffers, prefetch distance 2, one raw s_barrier
// per 32-K step.
__global__ __launch_bounds__(512, 2)
void gemm_proj(const bf16* __restrict__ A, const bf16* __restrict__ W,
               const float* __restrict__ bias, float* __restrict__ out) {
  __shared__ bf16 As[4][256 * 32];  // [buf][row*32 + chunk2*8], 16 KiB each
  __shared__ bf16 Bs[4][256 * 32];
  const int tid = threadIdx.x, lane = tid & 63, wid = tid >> 6;
  const int quad = lane >> 4, r15 = lane & 15;

  const int nbx = (int)gridDim.x;
  const int wg = xcd_chunk((int)blockIdx.y * nbx + (int)blockIdx.x,
                           nbx * (int)gridDim.y);
  const int m0 = (wg / nbx) * 256, n0 = (wg % nbx) * 256;

  const int rm = (wid >> 2) * 128;  // wave row base (2 waves in M)
  const int rn = (wid & 3) * 64;    // wave col base (4 waves in N)

  int aOff[2], bOff[2];
#pragma unroll
  for (int i = 0; i < 2; ++i) {
    int slot = i * 512 + tid;
    int row = slot >> 2, pc2 = slot & 3;
    int gc2 = pc2 ^ ((row ^ (row >> 2)) & 3);
    aOff[i] = (m0 + row) * CH + gc2 * 8;
    bOff[i] = (n0 + row) * CH + gc2 * 8;
  }

  f32x4 acc[8][4];
#pragma unroll
  for (int i = 0; i < 8; ++i)
#pragma unroll
    for (int j = 0; j < 4; ++j) acc[i][j] = (f32x4){0.f, 0.f, 0.f, 0.f};

#define ISSUE2(S)                                                              \
  {                                                                            \
    const int kb_ = (S) * 32;                                                  \
    const int bf_ = (S) & 3;                                                   \
    _Pragma("unroll") for (int i = 0; i < 2; ++i) {                            \
      async_ld16(A + aOff[i] + kb_, &As[bf_][(i * 512 + tid) * 8]);            \
      async_ld16(W + bOff[i] + kb_, &Bs[bf_][(i * 512 + tid) * 8]);            \
    }                                                                          \
  }

#define COMPUTE2(BF)                                                           \
  {                                                                            \
    bf16x8 bfr[4], afr[8];                                                     \
    _Pragma("unroll") for (int sn = 0; sn < 4; ++sn) {                         \
      int fr = rn + sn * 16 + r15;                                             \
      int pc2 = quad ^ ((fr ^ (fr >> 2)) & 3);                                 \
      bfr[sn] = *(const bf16x8*)(&Bs[BF][fr * 32 + pc2 * 8]);                  \
    }                                                                          \
    _Pragma("unroll") for (int sm = 0; sm < 8; ++sm) {                         \
      int fr = rm + sm * 16 + r15;                                             \
      int pc2 = quad ^ ((fr ^ (fr >> 2)) & 3);                                 \
      afr[sm] = *(const bf16x8*)(&As[BF][fr * 32 + pc2 * 8]);                  \
    }                                                                          \
    _Pragma("unroll") for (int sm = 0; sm < 8; ++sm)                           \
      _Pragma("unroll") for (int sn = 0; sn < 4; ++sn)                         \
        acc[sm][sn] = MFMA_BF16(afr[sm], bfr[sn], acc[sm][sn]);                \
  }

  ISSUE2(0);
  ISSUE2(1);
  for (int s = 0; s < NSTEP; ++s) {
    if (s < NSTEP - 2) {
      ISSUE2(s + 2);
      asm volatile("s_waitcnt vmcnt(8)" ::: "memory");
    } else if (s == NSTEP - 2) {
      asm volatile("s_waitcnt vmcnt(4)" ::: "memory");
    } else {
      asm volatile("s_waitcnt vmcnt(0)" ::: "memory");
    }
    __builtin_amdgcn_s_barrier();
    asm volatile("" ::: "memory");
    COMPUTE2(s & 3);
  }

  // epilogue: bias + fp32 out
#pragma unroll
  for (int sn = 0; sn < 4; ++sn) {
    int gn = n0 + rn + sn * 16 + r15;
    float bv = bias[gn];
#pragma unroll
    for (int sm = 0; sm < 8; ++sm) {
      int gmBase = m0 + rm + sm * 16 + quad * 4;
#pragma unroll
      for (int r = 0; r < 4; ++r) {
        int gm = gmBase + r;
        if (gm < MROWS) out[(size_t)gm * CH + gn] = acc[sm][sn][r] + bv;
      }
    }
  }
}
#undef ISSUE2
#undef COMPUTE2

// ---- flash attention, NO-MAX softmax, base-2 domain, swapped QK^T (R6),
// async double-buffered staging (R7), XCD-chunked blocks (R8), tail peel (R9).
// R11: MFMA ONES-TRICK ROW SUMS. rowsum(P) = P x ones computed by 4 extra MFMA
// per wave-tile on the 15%-utilized matrix pipe (pf fragments already loaded),
// replacing 64 VALU adds/wave/tile (the dominant-pipe cost: attn VALU ~600
// cyc/wave/tile of a ~1040 budget) AND the end-of-kernel shuffle reduce + per-row
// __shfl: the MFMA C/D layout lands rowsum(m=quad*4+r) in sacc[r] at exactly the
// lanes that write row m. Denominator now sums the same bf16-rounded P used in
// the numerator (consistency >= before).
__global__ __launch_bounds__(256, 3)
void attn_kernel(const bf16* __restrict__ qrm, const bf16* __restrict__ krm,
                 const bf16* __restrict__ vt, bf16* __restrict__ ob) {
  __shared__ bf16 Ks[2][128 * 32];     // K tile [hr = j_loc*2+half][32], XOR-swizzled
  __shared__ bf16 Vt[2][128 * 32];     // V^T tile [hr = d*2+half][32], XOR-swizzled
  __shared__ bf16 Ps[4][2][16 * 72];   // per-wave, per-group private P [m][j] pad 72
  const int tid = threadIdx.x, lane = tid & 63, wid = tid >> 6;
  const int quad = lane >> 4, r15 = lane & 15;
  const int nbx = (int)gridDim.x;  // 5
  const int wg = xcd_chunk((int)blockIdx.y * nbx + (int)blockIdx.x,
                           nbx * (int)gridDim.y);
  const int qt = wg % nbx, bh = wg / nbx;
  const int b_ = bh / NH, h = bh - b_ * NH;
  const bf16* vtb = vt + (size_t)bh * DHD * SEQP;
  const bf16* krmb = krm + (size_t)b_ * SEQ * CH + h * DHD;

  // Per-thread staging: slot q = wid*128 + c*64 + lane -> hr = q>>2 in [0,128),
  // logical chunk kc = (q&3)^sw(hr); element offset off = (hr&1)*32 + kc*8.
  // Running pointers advance +64*CH (K) / +64 (V) per clean tile.
  int jloc_[2], off_[2];
  const bf16* kp_[2];
  const bf16* vp_[2];
#pragma unroll
  for (int c = 0; c < 2; ++c) {
    int q = wid * 128 + c * 64 + lane;
    int hr = q >> 2;
    int kc = (q & 3) ^ ((hr ^ (hr >> 2)) & 3);
    jloc_[c] = hr >> 1;                    // K: local j row; V: d row
    off_[c] = (hr & 1) * 32 + kc * 8;      // K: d offset;   V: local j offset
    kp_[c] = krmb + (size_t)jloc_[c] * CH + off_[c];
    vp_[c] = vtb + (size_t)jloc_[c] * SEQP + off_[c];
  }

#define ASTAGE_CLEAN(BUF)                                                      \
  {                                                                            \
    _Pragma("unroll") for (int c = 0; c < 2; ++c) {                            \
      async_ld16(kp_[c], &Ks[BUF][(wid * 128 + c * 64) * 8]);                  \
      async_ld16(vp_[c], &Vt[BUF][(wid * 128 + c * 64) * 8]);                  \
      kp_[c] += 64 * CH;                                                       \
      vp_[c] += 64;                                                            \
    }                                                                          \
  }

  // Tile 9 (j0=576): every K row and V chunk start clamps to j=576.
#define ASTAGE_TAIL(BUF)                                                       \
  {                                                                            \
    _Pragma("unroll") for (int c = 0; c < 2; ++c) {                            \
      async_ld16(krmb + (size_t)(SEQ - 1) * CH + off_[c],                      \
                 &Ks[BUF][(wid * 128 + c * 64) * 8]);                          \
      async_ld16(vtb + (size_t)jloc_[c] * SEQP + (SEQ - 1),                    \
                 &Vt[BUF][(wid * 128 + c * 64) * 8]);                          \
    }                                                                          \
  }

  // Q fragments resident for both row groups (MFMA B operand: n=lane&15=q-row,
  // k=quad*8+j). q pre-scaled by 0.125*log2e.
  bf16x8 qf[2][2];
#pragma unroll
  for (int g = 0; g < 2; ++g) {
    int qrow = qt * 128 + wid * 32 + g * 16 + r15;
    if (qrow > SEQ - 1) qrow = SEQ - 1;
    const bf16* qp = qrm + (size_t)(b_ * SEQ + qrow) * CH + h * DHD + quad * 8;
    qf[g][0] = *(const bf16x8*)qp;
    qf[g][1] = *(const bf16x8*)(qp + 32);
  }

  // all-ones B fragment for the rowsum MFMA
  bf16x8 ones;
#pragma unroll
  for (int i = 0; i < 8; ++i) ones[i] = (bf16)1.0f;

  f32x4 oacc[2][4];
#pragma unroll
  for (int g = 0; g < 2; ++g)
#pragma unroll
    for (int i = 0; i < 4; ++i) oacc[g][i] = (f32x4){0.f, 0.f, 0.f, 0.f};
  f32x4 sacc0 = (f32x4){0.f, 0.f, 0.f, 0.f};  // rowsum accumulators (P x ones)
  f32x4 sacc1 = (f32x4){0.f, 0.f, 0.f, 0.f};

  bf16* P0 = &Ps[wid][0][0];
  bf16* P1 = &Ps[wid][1][0];

  // Shared compute body. MASKED=1 only for tile 9 (j0=576).
#define QKT_PV(BUF, MASKED)                                                    \
  {                                                                            \
    f32x4 s0[4], s1[4];                                                        \
    _Pragma("unroll") for (int sj = 0; sj < 4; ++sj) {                         \
      int hr0 = (sj * 16 + r15) * 2, hr1 = hr0 + 1;                            \
      int p0c = quad ^ ((hr0 ^ (hr0 >> 2)) & 3);                               \
      int p1c = quad ^ ((hr1 ^ (hr1 >> 2)) & 3);                               \
      bf16x8 kf0 = *(const bf16x8*)(&Ks[BUF][hr0 * 32 + p0c * 8]);             \
      bf16x8 kf1 = *(const bf16x8*)(&Ks[BUF][hr1 * 32 + p1c * 8]);             \
      f32x4 z = (f32x4){0.f, 0.f, 0.f, 0.f};                                   \
      s0[sj] = MFMA_BF16(kf0, qf[0][0], z);                                    \
      s0[sj] = MFMA_BF16(kf1, qf[0][1], s0[sj]);                               \
      s1[sj] = MFMA_BF16(kf0, qf[1][0], z);                                    \
      s1[sj] = MFMA_BF16(kf1, qf[1][1], s1[sj]);                               \
    }                                                                          \
    _Pragma("unroll") for (int sj = 0; sj < 4; ++sj)                           \
      _Pragma("unroll") for (int r = 0; r < 4; ++r) {                          \
        if (MASKED) {                                                          \
          bool ok = (sj == 0) && (quad == 0) && (r == 0); /* j==576 only */    \
          s0[sj][r] = ok ? __builtin_amdgcn_exp2f(s0[sj][r]) : 0.f;            \
          s1[sj][r] = ok ? __builtin_amdgcn_exp2f(s1[sj][r]) : 0.f;            \
        } else {                                                               \
          s0[sj][r] = __builtin_amdgcn_exp2f(s0[sj][r]);                       \
          s1[sj][r] = __builtin_amdgcn_exp2f(s1[sj][r]);                       \
        }                                                                      \
      }                                                                        \
    _Pragma("unroll") for (int sj = 0; sj < 4; ++sj) {                         \
      bf16x4 p0 = {(bf16)s0[sj][0], (bf16)s0[sj][1],                           \
                   (bf16)s0[sj][2], (bf16)s0[sj][3]};                          \
      bf16x4 p1 = {(bf16)s1[sj][0], (bf16)s1[sj][1],                           \
                   (bf16)s1[sj][2], (bf16)s1[sj][3]};                          \
      *(bf16x4*)(P0 + r15 * 72 + sj * 16 + quad * 4) = p0;                     \
      *(bf16x4*)(P1 + r15 * 72 + sj * 16 + quad * 4) = p1;                     \
    }                                                                          \
    asm volatile("s_waitcnt lgkmcnt(0)" ::: "memory"); /* wave-private RAW */  \
    _Pragma("unroll") for (int kc = 0; kc < 2; ++kc) {                         \
      bf16x8 pf0 = *(const bf16x8*)(P0 + r15 * 72 + kc * 32 + quad * 8);       \
      bf16x8 pf1 = *(const bf16x8*)(P1 + r15 * 72 + kc * 32 + quad * 8);       \
      sacc0 = MFMA_BF16(pf0, ones, sacc0);  /* rowsum += P slice x 1 */        \
      sacc1 = MFMA_BF16(pf1, ones, sacc1);                                     \
      _Pragma("unroll") for (int sd = 0; sd < 4; ++sd) {                       \
        int hrv = (sd * 16 + r15) * 2 + kc;                                    \
        int pv = quad ^ ((hrv ^ (hrv >> 2)) & 3);                              \
        bf16x8 vf = *(const bf16x8*)(&Vt[BUF][hrv * 32 + pv * 8]);             \
        oacc[0][sd] = MFMA_BF16(pf0, vf, oacc[0][sd]);                         \
        oacc[1][sd] = MFMA_BF16(pf1, vf, oacc[1][sd]);                         \
      }                                                                        \
    }                                                                          \
  }

  ASTAGE_CLEAN(0);
  int buf = 0;
  for (int t = 0; t < 9; ++t) {
    __syncthreads();  // drains stage(t) (issued one full tile ago) + buf reuse safe
    if (t < 8) { ASTAGE_CLEAN(buf ^ 1); } else { ASTAGE_TAIL(buf ^ 1); }
    QKT_PV(buf, 0);
    buf ^= 1;
  }
  __syncthreads();    // drains tile-9 stage
  QKT_PV(buf, 1);     // tile 9: only j=576 valid
#undef ASTAGE_CLEAN
#undef ASTAGE_TAIL
#undef QKT_PV

  // write O -> attn_out [b*577+n][h*64+d]; O C/D layout: row m=quad*4+r,
  // col d=sd*16+r15. sacc[r] already holds rowsum(m=quad*4+r) at THIS lane
  // (MFMA C/D layout, every column identical) -> no cross-lane ops needed.
#pragma unroll
  for (int g = 0; g < 2; ++g) {
#pragma unroll
    for (int r = 0; r < 4; ++r) {
      int m = quad * 4 + r;
      float rs = (g == 0) ? sacc0[r] : sacc1[r];
      int orow = qt * 128 + wid * 32 + g * 16 + m;
      if (orow < SEQ) {
        float inv = 1.0f / rs;
        size_t rowoff = ((size_t)(b_ * SEQ + orow)) * CH + h * DHD;
#pragma unroll
        for (int sd = 0; sd < 4; ++sd)
          ob[rowoff + sd * 16 + r15] = (bf16)(oacc[g][sd][r] * inv);
      }
    }
  }
}

extern "C" void kernel_launch(void* const* d_in, const int* in_sizes, int n_in,
                              void* d_out, int out_size, void* d_ws, size_t ws_size,
                              hipStream_t stream) {
  const float* x      = (const float*)d_in[0];
  const float* qkv_w  = (const float*)d_in[1];
  const float* qkv_b  = (const float*)d_in[2];
  const float* proj_w = (const float*)d_in[3];
  const float* proj_b = (const float*)d_in[4];
  float* out = (float*)d_out;

  char* w = (char*)d_ws;
  // workspace layout (bytes), total 117,325,824:
  bf16* xb  = (bf16*)(w);               // [18464,768] x_bf16, reused as attn_out
  bf16* wqp = (bf16*)(w + 28360704);    // qkv_w bf16; later aliased by proj_w bf16
  bf16* qrm = (bf16*)(w + 31899648);    // [18464,768] scaled Q
  bf16* krm = (bf16*)(w + 60260352);    // [18464,768] K
  bf16* vtb = (bf16*)(w + 88621056);    // [32,12,64,584] V^T
  // GEMM m-tail reads spill into the wqp region: finite, discarded.

  cvt_bf16<<<(MROWS * CH / 4 + 255) / 256, 256, 0, stream>>>(x, xb, MROWS * CH);
  cvt_bf16<<<(NQKV * CH / 4 + 255) / 256, 256, 0, stream>>>(qkv_w, wqp, NQKV * CH);
  pad_v<<<(BB * NH * DHD + 255) / 256, 256, 0, stream>>>(vtb);

  gemm_qkv<<<dim3(NQKV / 128, 145), 256, 0, stream>>>(
      xb, wqp, qkv_b, qrm, krm, vtb);

  attn_kernel<<<dim3(5, BB * NH), 256, 0, stream>>>(qrm, krm, vtb, xb);

  // proj weights convert AFTER attention (stream-ordered) so it can alias wqp
  cvt_bf16<<<(CH * CH / 4 + 255) / 256, 256, 0, stream>>>(proj_w, wqp, CH * CH);

  gemm_proj<<<dim3(CH / 256, 73), 512, 0, stream>>>(xb, wqp, proj_b, out);
}